// Round 5
// baseline (256.414 us; speedup 1.0000x reference)
//
#include <hip/hip_runtime.h>

#define NVOX 150000
#define BM 128
#define MTILES 1172         // ceil(150000/128)
#define SROW 150016         // 1172*128, column stride of h buffer
#define NCOL 320

typedef __attribute__((ext_vector_type(8))) short bf16x8;
typedef __attribute__((ext_vector_type(4))) float f32x4;

__device__ __forceinline__ unsigned short f2bf(float f) {
    unsigned u = __builtin_bit_cast(unsigned, f);
    u += 0x7fffu + ((u >> 16) & 1u);
    return (unsigned short)(u >> 16);
}

// ---------------- prep: features f32 -> bf16 (+ zero row at NVOX), x8 vectorized ------
__global__ void prep_feat(const float* __restrict__ src, unsigned short* __restrict__ dst) {
    int i = blockIdx.x * 256 + threadIdx.x;   // each i handles 8 elements
    if (i < NVOX * 8) {
        const float* s = src + (size_t)i * 8;
        float4 a = *(const float4*)s;
        float4 b = *(const float4*)(s + 4);
        union { bf16x8 v; unsigned short u[8]; } r;
        r.u[0] = f2bf(a.x); r.u[1] = f2bf(a.y); r.u[2] = f2bf(a.z); r.u[3] = f2bf(a.w);
        r.u[4] = f2bf(b.x); r.u[5] = f2bf(b.y); r.u[6] = f2bf(b.z); r.u[7] = f2bf(b.w);
        *(bf16x8*)(dst + (size_t)i * 8) = r.v;
    } else if (i < NVOX * 8 + 8) {            // zero row for invalid/pad gathers
        bf16x8 z = {0, 0, 0, 0, 0, 0, 0, 0};
        *(bf16x8*)(dst + (size_t)i * 8) = z;
    }
}

// ---- prep: W3[h][kk][c][o] f32 -> Bt2 chunk-major bf16: [(h*9+kk)*8 + c16][o][c&7] ----
__global__ void prep_w3(const float* __restrict__ w3, unsigned short* __restrict__ bt,
                        float* __restrict__ stats) {
    int i = blockIdx.x * 256 + threadIdx.x;   // grid is exactly 184320 threads
    int h = i / 36864;
    int rem = i - h * 36864;
    int kk = rem >> 12;
    int c = (rem >> 6) & 63;
    int o = rem & 63;
    bt[(size_t)(((h * 9 + kk) * 8) + (c >> 3)) * 512 + o * 8 + (c & 7)] = f2bf(w3[i]);
    if (i < 2 * NCOL) stats[i] = 0.f;
}

// ------------- gather-GEMM: LDS-FREE register streaming, NO barriers in K-loop --------
// All 5 heads per block; BM=128, N=320, 8 waves (512 thr), wave tile 64x80.
// A-fragment = 16 contiguous bytes of one featB row -> per-lane global_load_dwordx4
// straight to registers (16 rows x 64B fully-used lines per instr). B likewise (L2-hot).
// Fully unrolled K-loop with per-iteration SSA locals: the compiler software-pipelines
// loads across iterations up to the 256-VGPR budget; waves run completely independent -
// no s_barrier, no hand vmcnt, no bulk-synchronous stage/compute phase alternation
// (the structure that R0-R4 showed pins this kernel at ~95us regardless of traffic).
// LDS: transpose scratch [0,87040) + idx @87040 (4608B) + sred @91648 (5120B) = 96768.
__global__ __launch_bounds__(512, 2)
void gemm_kernel(const unsigned short* __restrict__ featB,
                 const unsigned short* __restrict__ Bt2,
                 const int* __restrict__ nbr,
                 unsigned short* __restrict__ hbuf,
                 float* __restrict__ stats) {
    __shared__ __align__(16) char smem[96768];
    constexpr int IDX_OFF = 87040;   // 9*128 int byte-offsets (outside transpose region)
    constexpr int SRED_OFF = 91648;  // 8*80*8 B stats staging

    int mtile = blockIdx.x;
    int m0 = mtile * BM;

    int tid = threadIdx.x;
    int w = tid >> 6, lane = tid & 63;
    int quad = lane >> 4, m16 = lane & 15;

    // ---- stage neighbor byte-offset table: sIdx[kk][row] = srow*128 ----
    for (int lin = tid; lin < BM * 9; lin += 512) {
        int row = lin / 9, kkq = lin - row * 9;
        int v = -1;
        if (m0 + row < NVOX) v = nbr[(size_t)(m0 + row) * 9 + kkq];
        *(int*)(smem + IDX_OFF + (kkq * BM + row) * 4) = ((v < 0) ? NVOX : v) * 128;
    }
    __syncthreads();    // idx table ready; only barrier before the epilogue

    f32x4 acc[4][5];
#pragma unroll
    for (int mt = 0; mt < 4; ++mt)
#pragma unroll
        for (int nt = 0; nt < 5; ++nt)
            acc[mt][nt] = (f32x4){0.f, 0.f, 0.f, 0.f};

    const char* fb = (const char*)featB;
    const char* bt = (const char*)Bt2;

    int mrow = (w >> 2) * 64;    // wave's row half (0/64)
    int cbase = (w & 3) * 80;    // wave's 80-col quarter of the 320 cols

    // per-lane global B fragment bases: col c -> head h=c>>6, o=c&63
    // addr = h*73728 + kk*8192 + (ks*4+quad)*1024 + o*16
    int bOff[5];
#pragma unroll
    for (int nt = 0; nt < 5; ++nt) {
        int c = cbase + nt * 16 + m16;
        bOff[nt] = (c >> 6) * 73728 + quad * 1024 + (c & 63) * 16;
    }
    const char* idxp = smem + IDX_OFF;

#pragma unroll
    for (int kk = 0; kk < 9; ++kk) {
        // fragment row byte-offsets (16 consecutive ints; quad-broadcast ds_read)
        int ro[4];
#pragma unroll
        for (int mt = 0; mt < 4; ++mt)
            ro[mt] = *(const int*)(idxp + (kk * BM + mrow + mt * 16 + m16) * 4);
        // A and B fragments straight to registers (per-iteration SSA locals)
        bf16x8 af[2][4], bf[2][5];
#pragma unroll
        for (int ks = 0; ks < 2; ++ks) {
#pragma unroll
            for (int mt = 0; mt < 4; ++mt)
                af[ks][mt] = *(const bf16x8*)(fb + ro[mt] + (ks * 4 + quad) * 16);
#pragma unroll
            for (int nt = 0; nt < 5; ++nt)
                bf[ks][nt] = *(const bf16x8*)(bt + bOff[nt] + kk * 8192 + ks * 4096);
        }
#pragma unroll
        for (int ks = 0; ks < 2; ++ks)
#pragma unroll
            for (int mt = 0; mt < 4; ++mt)
#pragma unroll
                for (int nt = 0; nt < 5; ++nt)
                    acc[mt][nt] = __builtin_amdgcn_mfma_f32_16x16x32_bf16(
                        af[ks][mt], bf[ks][nt], acc[mt][nt], 0, 0, 0);
    }

    // ---- epilogue 1: transpose via LDS ([0,87040), disjoint from idx), coalesced ----
#pragma unroll
    for (int mt = 0; mt < 4; ++mt) {
#pragma unroll
        for (int nt = 0; nt < 5; ++nt) {
            int col = cbase + nt * 16 + m16;
            int row = mrow + mt * 16 + quad * 4;
            f32x4 v = acc[mt][nt];
            unsigned lo = (unsigned)f2bf(v.x) | ((unsigned)f2bf(v.y) << 16);
            unsigned hi = (unsigned)f2bf(v.z) | ((unsigned)f2bf(v.w) << 16);
            uint2 pk; pk.x = lo; pk.y = hi;
            *(uint2*)(smem + col * 272 + row * 2) = pk;   // col stride 136 ushorts
        }
    }
    __syncthreads();
#pragma unroll
    for (int it = 0; it < 20; ++it) {                  // 320 cols = 20 x (16 cols x 32 ln)
        int col = it * 16 + (tid >> 5);
        int l32 = tid & 31;
        uint2 v = *(const uint2*)(smem + col * 272 + l32 * 8);
        *(uint2*)(hbuf + (size_t)col * SROW + m0 + l32 * 4) = v;  // 256B runs
    }

    // ---- epilogue 2: BN statistics (pad/invalid rows are exact zeros) ----
    float s[5], ss[5];
#pragma unroll
    for (int nt = 0; nt < 5; ++nt) {
        float a = 0.f, b = 0.f;
#pragma unroll
        for (int mt = 0; mt < 4; ++mt) {
            f32x4 v = acc[mt][nt];
            a += v.x + v.y + v.z + v.w;
            b += v.x * v.x + v.y * v.y + v.z * v.z + v.w * v.w;
        }
        s[nt] = a; ss[nt] = b;
        s[nt] += __shfl_xor(s[nt], 16); s[nt] += __shfl_xor(s[nt], 32);
        ss[nt] += __shfl_xor(ss[nt], 16); ss[nt] += __shfl_xor(ss[nt], 32);
    }
    if (quad == 0) {   // SRED region (91648+) disjoint from transpose + idx
#pragma unroll
        for (int nt = 0; nt < 5; ++nt) {
            float* p = (float*)(smem + SRED_OFF + (w * 80 + nt * 16 + m16) * 8);
            p[0] = s[nt]; p[1] = ss[nt];
        }
    }
    __syncthreads();
    if (tid < NCOL) {
        int c = tid;
        int qq = c / 80, lc = c - qq * 80;   // waves qq (rows 0-63) and qq+4 (64-127)
        const float* p0 = (const float*)(smem + SRED_OFF + (qq * 80 + lc) * 8);
        const float* p1 = (const float*)(smem + SRED_OFF + ((qq + 4) * 80 + lc) * 8);
        atomicAdd(&stats[c], p0[0] + p1[0]);
        atomicAdd(&stats[NCOL + c], p0[1] + p1[1]);
    }
}

// ------- pass 2: BN + ReLU + 1x1 conv, per-HEAD grid (5x parallelism, 64 loads/thread)
__global__ __launch_bounds__(256)
void head_kernel(const unsigned short* __restrict__ hbuf,
                 const float* __restrict__ stats,
                 const float* __restrict__ gamma, const float* __restrict__ beta,
                 const float* __restrict__ W1_0, const float* __restrict__ W1_1,
                 const float* __restrict__ W1_2, const float* __restrict__ W1_3,
                 const float* __restrict__ W1_4,
                 const float* __restrict__ b1_0, const float* __restrict__ b1_1,
                 const float* __restrict__ b1_2, const float* __restrict__ b1_3,
                 const float* __restrict__ b1_4,
                 float* __restrict__ out) {
    __shared__ float sScale[64], sShift[64], sW1[192], sB1[3];
    int h = blockIdx.y;
    const float* W1; const float* b1; int oc; size_t obase;
    if (h == 0)      { W1 = W1_0; b1 = b1_0; oc = 3; obase = 0; }
    else if (h == 1) { W1 = W1_1; b1 = b1_1; oc = 2; obase = 450000; }
    else if (h == 2) { W1 = W1_2; b1 = b1_2; oc = 1; obase = 750000; }
    else if (h == 3) { W1 = W1_3; b1 = b1_3; oc = 3; obase = 900000; }
    else             { W1 = W1_4; b1 = b1_4; oc = 2; obase = 1350000; }

    int tid = threadIdx.x;
    if (tid < 64) {
        int c = h * 64 + tid;
        float mean = stats[c] * (1.f / (float)NVOX);
        float var = stats[NCOL + c] * (1.f / (float)NVOX) - mean * mean;
        float inv = rsqrtf(var + 1e-5f);
        float sc = inv * gamma[c];
        sScale[tid] = sc;
        sShift[tid] = beta[c] - mean * sc;
    }
    for (int i = tid; i < 192; i += 256) {
        int cc = i / 3, jj = i - cc * 3;
        sW1[i] = (jj < oc) ? W1[cc * oc + jj] : 0.f;
    }
    if (tid == 0) {
        sB1[0] = b1[0];
        sB1[1] = (oc >= 2) ? b1[1] : 0.f;
        sB1[2] = (oc >= 3) ? b1[2] : 0.f;
    }
    __syncthreads();

    int n = (blockIdx.x * 256 + tid) * 4;    // 4 rows per thread (NVOX % 4 == 0)
    if (n >= NVOX) return;
    const unsigned short* hp = hbuf + (size_t)(h * 64) * SROW + n;
    float x[4][3];
#pragma unroll
    for (int rr = 0; rr < 4; ++rr) { x[rr][0] = sB1[0]; x[rr][1] = sB1[1]; x[rr][2] = sB1[2]; }
#pragma unroll 8
    for (int cc = 0; cc < 64; ++cc) {
        uint2 raw = *(const uint2*)(hp + (size_t)cc * SROW);   // rows n..n+3, bf16
        float sc = sScale[cc], sh = sShift[cc];
        float w0 = sW1[cc * 3 + 0], w1 = sW1[cc * 3 + 1], w2 = sW1[cc * 3 + 2];
        float v0 = __builtin_bit_cast(float, raw.x << 16);
        float v1 = __builtin_bit_cast(float, raw.x & 0xffff0000u);
        float v2 = __builtin_bit_cast(float, raw.y << 16);
        float v3 = __builtin_bit_cast(float, raw.y & 0xffff0000u);
        v0 = fmaxf(v0 * sc + sh, 0.f); v1 = fmaxf(v1 * sc + sh, 0.f);
        v2 = fmaxf(v2 * sc + sh, 0.f); v3 = fmaxf(v3 * sc + sh, 0.f);
        x[0][0] += v0 * w0; x[0][1] += v0 * w1; x[0][2] += v0 * w2;
        x[1][0] += v1 * w0; x[1][1] += v1 * w1; x[1][2] += v1 * w2;
        x[2][0] += v2 * w0; x[2][1] += v2 * w1; x[2][2] += v2 * w2;
        x[3][0] += v3 * w0; x[3][1] += v3 * w1; x[3][2] += v3 * w2;
    }
#pragma unroll
    for (int rr = 0; rr < 4; ++rr) {
        float* op = out + obase + (size_t)(n + rr) * oc;
        op[0] = x[rr][0];                 // oc is block-uniform; x indices all static
        if (oc >= 2) op[1] = x[rr][1];
        if (oc >= 3) op[2] = x[rr][2];
    }
}

extern "C" void kernel_launch(void* const* d_in, const int* in_sizes, int n_in,
                              void* d_out, int out_size, void* d_ws, size_t ws_size,
                              hipStream_t stream) {
    const float* features = (const float*)d_in[0];
    const int* nbr        = (const int*)d_in[1];
    const float* w3       = (const float*)d_in[2];
    const float* gamma    = (const float*)d_in[3];
    const float* beta     = (const float*)d_in[4];
    const float* W1_0 = (const float*)d_in[5];  const float* b1_0 = (const float*)d_in[6];
    const float* W1_1 = (const float*)d_in[7];  const float* b1_1 = (const float*)d_in[8];
    const float* W1_2 = (const float*)d_in[9];  const float* b1_2 = (const float*)d_in[10];
    const float* W1_3 = (const float*)d_in[11]; const float* b1_3 = (const float*)d_in[12];
    const float* W1_4 = (const float*)d_in[13]; const float* b1_4 = (const float*)d_in[14];
    float* out = (float*)d_out;

    char* ws = (char*)d_ws;
    unsigned short* featB = (unsigned short*)ws;               // (150000+1)*64 bf16
    unsigned short* Bt2   = (unsigned short*)(ws + 19200128);  // 5*9*8*512 bf16
    float* stats          = (float*)(ws + 19568768);           // 640 f32
    unsigned short* hbuf  = (unsigned short*)(ws + 19571328);  // 320*150016 bf16

    prep_feat<<<(NVOX * 8 + 8 + 255) / 256, 256, 0, stream>>>(features, featB);
    prep_w3<<<184320 / 256, 256, 0, stream>>>(w3, Bt2, stats);
    gemm_kernel<<<MTILES, 512, 0, stream>>>(featB, Bt2, nbr, hbuf, stats);
    head_kernel<<<dim3(147, 5), 256, 0, stream>>>(hbuf, stats, gamma, beta,
        W1_0, W1_1, W1_2, W1_3, W1_4, b1_0, b1_1, b1_2, b1_3, b1_4, out);
}

// Round 6
// 250.766 us; speedup vs baseline: 1.0225x; 1.0225x over previous
//
#include <hip/hip_runtime.h>

#define NVOX 150000
#define BM 128
#define MTILES 1172         // ceil(150000/128)
#define SROW 150016         // 1172*128, column stride of h buffer
#define NCOL 320

typedef __attribute__((ext_vector_type(8))) short bf16x8;
typedef __attribute__((ext_vector_type(4))) float f32x4;

__device__ __forceinline__ unsigned short f2bf(float f) {
    unsigned u = __builtin_bit_cast(unsigned, f);
    u += 0x7fffu + ((u >> 16) & 1u);
    return (unsigned short)(u >> 16);
}

__device__ __forceinline__ void gld16(const void* g, void* l) {
    __builtin_amdgcn_global_load_lds(
        (const __attribute__((address_space(1))) unsigned int*)g,
        (__attribute__((address_space(3))) unsigned int*)l, 16, 0, 0);
}

// ---------------- prep: features f32 -> bf16 (+ zero row at NVOX), x8 vectorized ------
__global__ void prep_feat(const float* __restrict__ src, unsigned short* __restrict__ dst) {
    int i = blockIdx.x * 256 + threadIdx.x;   // each i handles 8 elements
    if (i < NVOX * 8) {
        const float* s = src + (size_t)i * 8;
        float4 a = *(const float4*)s;
        float4 b = *(const float4*)(s + 4);
        union { bf16x8 v; unsigned short u[8]; } r;
        r.u[0] = f2bf(a.x); r.u[1] = f2bf(a.y); r.u[2] = f2bf(a.z); r.u[3] = f2bf(a.w);
        r.u[4] = f2bf(b.x); r.u[5] = f2bf(b.y); r.u[6] = f2bf(b.z); r.u[7] = f2bf(b.w);
        *(bf16x8*)(dst + (size_t)i * 8) = r.v;
    } else if (i < NVOX * 8 + 8) {            // zero row for invalid/pad gathers
        bf16x8 z = {0, 0, 0, 0, 0, 0, 0, 0};
        *(bf16x8*)(dst + (size_t)i * 8) = z;
    }
}

// ---- prep: W3[h][kk][c][o] f32 -> Bt2 chunk-major bf16: [(h*9+kk)*8 + c16][o][c&7] ----
__global__ void prep_w3(const float* __restrict__ w3, unsigned short* __restrict__ bt,
                        float* __restrict__ stats) {
    int i = blockIdx.x * 256 + threadIdx.x;   // grid is exactly 184320 threads
    int h = i / 36864;
    int rem = i - h * 36864;
    int kk = rem >> 12;
    int c = (rem >> 6) & 63;
    int o = rem & 63;
    bt[(size_t)(((h * 9 + kk) * 8) + (c >> 3)) * 512 + o * 8 + (c & 7)] = f2bf(w3[i]);
    if (i < 2 * NCOL) stats[i] = 0.f;   // needed only for the atomic fallback path
}

// ---------------- gather-GEMM: R4 core + NON-ATOMIC stats (the R0-R5 invariant) -------
// R0-R5 showed gemm pinned at ~95us across 6x traffic / 20x request / 5x occupancy /
// all barrier-structure changes. The one bit-identical piece was the epilogue's 750k
// device atomicAdds into 640 floats (~40 lines) -> same-line L2 RMW serialization is
// the theorized ~95us floor. This round: per-block coalesced partial writes
// (partials[mtile][640]) + separate reduce kernel. Atomic path kept as ws_size fallback.
__global__ __launch_bounds__(512, 2)
void gemm_kernel(const unsigned short* __restrict__ featB,
                 const unsigned short* __restrict__ Bt2,
                 const int* __restrict__ nbr,
                 unsigned short* __restrict__ hbuf,
                 float* __restrict__ stats,
                 float* __restrict__ partials) {
    __shared__ __align__(16) char smem[119296];
    constexpr int SB_OFF = 32768;    // B dbuf 2x40960
    constexpr int IDX_OFF = 114688;  // 9*128 int byte-offsets (4608 B)
    constexpr int SRED_OFF = 88064;  // stats staging 8*80*8 B; above transpose's 87040

    int mtile = blockIdx.x;
    int m0 = mtile * BM;

    int tid = threadIdx.x;
    int w = tid >> 6, lane = tid & 63;
    int quad = lane >> 4, m16 = lane & 15;

    // ---- stage neighbor byte-offset table: sIdx[kk][row] = srow*128 ----
    for (int lin = tid; lin < BM * 9; lin += 512) {
        int row = lin / 9, kkq = lin - row * 9;
        int v = -1;
        if (m0 + row < NVOX) v = nbr[(size_t)(m0 + row) * 9 + kkq];
        *(int*)(smem + IDX_OFF + (kkq * BM + row) * 4) = ((v < 0) ? NVOX : v) * 128;
    }
    __syncthreads();

    f32x4 acc[4][5];
#pragma unroll
    for (int mt = 0; mt < 4; ++mt)
#pragma unroll
        for (int nt = 0; nt < 5; ++nt)
            acc[mt][nt] = (f32x4){0.f, 0.f, 0.f, 0.f};

    const char* fb = (const char*)featB;
    const char* bt = (const char*)Bt2;
    char* sAb[2] = {smem, smem + 16384};
    char* sBb[2] = {smem + SB_OFF, smem + SB_OFF + 40960};

    int mrow = (w >> 2) * 64;    // wave's row half (0/64)
    int cbase = (w & 3) * 80;    // wave's 80-col quarter of the 320 cols

    // gather geometry: 8 lanes per row; lane = rloc*8 + j
    int rloc = lane >> 3, j = lane & 7;
    int jx = (j ^ rloc) * 16;    // source-chunk XOR swizzle ((row&7) == rloc)

    // B stage units for this wave: u = w*5+j -> (head, c16); 8 waves x 5 = 40 KB/kk
    int bsj[5], bdj[5];
#pragma unroll
    for (int jj = 0; jj < 5; ++jj) {
        int u = w * 5 + jj;
        int h = u >> 3, c16 = u & 7;
        bsj[jj] = (h * 72 + c16) * 1024 + lane * 16;  // + kk*8192 per tile
        bdj[jj] = (h * 8 + c16) * 1024;
    }
    // per-lane B-frag byte offsets within sB: col -> (head, o) chunk-major
    int sBoff[5];
#pragma unroll
    for (int nt = 0; nt < 5; ++nt) {
        int c = cbase + nt * 16 + m16;
        sBoff[nt] = (c >> 6) * 8192 + (c & 63) * 16;
    }
    // per-lane A-frag row bases (row-major) + XOR term per ds_read
    int aRow[4];
#pragma unroll
    for (int mt = 0; mt < 4; ++mt)
        aRow[mt] = (mrow + mt * 16 + m16) * 128;
    int axor = m16 & 7;          // == row & 7 for all frag rows

    auto stage = [&](int buf, int kk) {
        char* sA = sAb[buf];
        char* sB = sBb[buf];
        // A: wave w stages rows w*16 .. w*16+15 (2 instr x 8 full rows); per-lane src
        // addr = rowbase + swizzled chunk; LDS dst wave-uniform (HW adds lane*16)
        int off0 = *(const int*)(smem + IDX_OFF + (kk * BM + w * 16 + rloc) * 4);
        int off1 = *(const int*)(smem + IDX_OFF + (kk * BM + w * 16 + 8 + rloc) * 4);
        gld16(fb + off0 + jx, sA + w * 2048);
        gld16(fb + off1 + jx, sA + w * 2048 + 1024);
        // B: 5 sequential 1KB copies (chunk-major source), L2-hot
#pragma unroll
        for (int jj = 0; jj < 5; ++jj)
            gld16(bt + (size_t)(bsj[jj] + kk * 8192), sB + bdj[jj]);
    };

    // prologue: stage tile 0 (7 vm ops in flight)
    stage(0, 0);

#pragma unroll
    for (int kk = 0; kk < 9; ++kk) {
        const int p = kk & 1;
        if (kk < 8) {
            stage(p ^ 1, kk + 1);                      // 7 more vm ops (14 in flight)
            asm volatile("s_waitcnt vmcnt(7)" ::: "memory");  // tile kk done; kk+1 flies
        } else {
            asm volatile("s_waitcnt vmcnt(0)" ::: "memory");
        }
        asm volatile("s_barrier" ::: "memory");        // raw barrier: NO vmcnt drain
        __builtin_amdgcn_sched_barrier(0);             // rule 18: pin ds_read/MFMA below
        __builtin_amdgcn_s_setprio(1);
#pragma unroll
        for (int ks = 0; ks < 2; ++ks) {
            bf16x8 af[4], bf[5];
            int xq = ((ks * 4 + quad) ^ axor) * 16;    // swizzled chunk within row
#pragma unroll
            for (int mt = 0; mt < 4; ++mt)
                af[mt] = *(const bf16x8*)(sAb[p] + aRow[mt] + xq);
#pragma unroll
            for (int nt = 0; nt < 5; ++nt)
                bf[nt] = *(const bf16x8*)(sBb[p] + sBoff[nt] + (ks * 4 + quad) * 1024);
#pragma unroll
            for (int mt = 0; mt < 4; ++mt)
#pragma unroll
                for (int nt = 0; nt < 5; ++nt)
                    acc[mt][nt] = __builtin_amdgcn_mfma_f32_16x16x32_bf16(
                        af[mt], bf[nt], acc[mt][nt], 0, 0, 0);
        }
        __builtin_amdgcn_s_setprio(0);
        __builtin_amdgcn_sched_barrier(0);
        asm volatile("s_barrier" ::: "memory");        // sAb[p]/sBb[p] free to restage
    }

    // ---- epilogue 1: transpose via LDS (aliases dead sA/sB), coalesced column stores
#pragma unroll
    for (int mt = 0; mt < 4; ++mt) {
#pragma unroll
        for (int nt = 0; nt < 5; ++nt) {
            int col = cbase + nt * 16 + m16;
            int row = mrow + mt * 16 + quad * 4;
            f32x4 v = acc[mt][nt];
            unsigned lo = (unsigned)f2bf(v.x) | ((unsigned)f2bf(v.y) << 16);
            unsigned hi = (unsigned)f2bf(v.z) | ((unsigned)f2bf(v.w) << 16);
            uint2 pk; pk.x = lo; pk.y = hi;
            *(uint2*)(smem + col * 272 + row * 2) = pk;   // col stride 136 ushorts
        }
    }
    __syncthreads();
#pragma unroll
    for (int it = 0; it < 20; ++it) {                  // 320 cols = 20 x (16 cols x 32 ln)
        int col = it * 16 + (tid >> 5);
        int l32 = tid & 31;
        uint2 v = *(const uint2*)(smem + col * 272 + l32 * 8);
        *(uint2*)(hbuf + (size_t)col * SROW + m0 + l32 * 4) = v;  // 256B runs
    }

    // ---- epilogue 2: BN statistics (pad/invalid rows are exact zeros) ----
    float s[5], ss[5];
#pragma unroll
    for (int nt = 0; nt < 5; ++nt) {
        float a = 0.f, b = 0.f;
#pragma unroll
        for (int mt = 0; mt < 4; ++mt) {
            f32x4 v = acc[mt][nt];
            a += v.x + v.y + v.z + v.w;
            b += v.x * v.x + v.y * v.y + v.z * v.z + v.w * v.w;
        }
        s[nt] = a; ss[nt] = b;
        s[nt] += __shfl_xor(s[nt], 16); s[nt] += __shfl_xor(s[nt], 32);
        ss[nt] += __shfl_xor(ss[nt], 16); ss[nt] += __shfl_xor(ss[nt], 32);
    }
    if (quad == 0) {   // SRED region (88064+) does not alias transpose data (<87040)
#pragma unroll
        for (int nt = 0; nt < 5; ++nt) {
            float* p = (float*)(smem + SRED_OFF + (w * 80 + nt * 16 + m16) * 8);
            p[0] = s[nt]; p[1] = ss[nt];
        }
    }
    __syncthreads();
    if (tid < NCOL) {
        int c = tid;
        int qq = c / 80, lc = c - qq * 80;   // waves qq (rows 0-63) and qq+4 (64-127)
        const float* p0 = (const float*)(smem + SRED_OFF + (qq * 80 + lc) * 8);
        const float* p1 = (const float*)(smem + SRED_OFF + ((qq + 4) * 80 + lc) * 8);
        float vsum = p0[0] + p1[0];
        float vss  = p0[1] + p1[1];
        if (partials) {
            // coalesced per-block partial write: NO atomics (removes the L2 same-line
            // RMW serialization theorized as the ~95us structural floor)
            float* pp = partials + (size_t)mtile * (2 * NCOL);
            pp[c] = vsum;
            pp[NCOL + c] = vss;
        } else {
            atomicAdd(&stats[c], vsum);
            atomicAdd(&stats[NCOL + c], vss);
        }
    }
}

// ---- stats_reduce: stats[j] = sum_m partials[m][j]; 20 blocks x 256 thr, coalesced ----
__global__ __launch_bounds__(256)
void stats_reduce(const float* __restrict__ partials, float* __restrict__ stats) {
    __shared__ float red[256];
    int b = blockIdx.x;              // 0..19, each owns 32 of the 640 columns
    int tid = threadIdx.x;
    int cl = tid & 31;               // col within block
    int chunk = tid >> 5;            // 0..7 mtile-chunks
    int jcol = b * 32 + cl;          // 0..639
    float s = 0.f;
    int m1 = chunk * 147 + 147; if (m1 > MTILES) m1 = MTILES;
    for (int m = chunk * 147; m < m1; ++m)
        s += partials[(size_t)m * (2 * NCOL) + jcol];
    red[tid] = s;
    __syncthreads();
    if (tid < 32) {
        float a = red[tid];
#pragma unroll
        for (int k = 1; k < 8; ++k) a += red[k * 32 + tid];
        stats[b * 32 + tid] = a;
    }
}

// ------- pass 2: BN + ReLU + 1x1 conv, per-HEAD grid (5x parallelism, 64 loads/thread)
__global__ __launch_bounds__(256)
void head_kernel(const unsigned short* __restrict__ hbuf,
                 const float* __restrict__ stats,
                 const float* __restrict__ gamma, const float* __restrict__ beta,
                 const float* __restrict__ W1_0, const float* __restrict__ W1_1,
                 const float* __restrict__ W1_2, const float* __restrict__ W1_3,
                 const float* __restrict__ W1_4,
                 const float* __restrict__ b1_0, const float* __restrict__ b1_1,
                 const float* __restrict__ b1_2, const float* __restrict__ b1_3,
                 const float* __restrict__ b1_4,
                 float* __restrict__ out) {
    __shared__ float sScale[64], sShift[64], sW1[192], sB1[3];
    int h = blockIdx.y;
    const float* W1; const float* b1; int oc; size_t obase;
    if (h == 0)      { W1 = W1_0; b1 = b1_0; oc = 3; obase = 0; }
    else if (h == 1) { W1 = W1_1; b1 = b1_1; oc = 2; obase = 450000; }
    else if (h == 2) { W1 = W1_2; b1 = b1_2; oc = 1; obase = 750000; }
    else if (h == 3) { W1 = W1_3; b1 = b1_3; oc = 3; obase = 900000; }
    else             { W1 = W1_4; b1 = b1_4; oc = 2; obase = 1350000; }

    int tid = threadIdx.x;
    if (tid < 64) {
        int c = h * 64 + tid;
        float mean = stats[c] * (1.f / (float)NVOX);
        float var = stats[NCOL + c] * (1.f / (float)NVOX) - mean * mean;
        float inv = rsqrtf(var + 1e-5f);
        float sc = inv * gamma[c];
        sScale[tid] = sc;
        sShift[tid] = beta[c] - mean * sc;
    }
    for (int i = tid; i < 192; i += 256) {
        int cc = i / 3, jj = i - cc * 3;
        sW1[i] = (jj < oc) ? W1[cc * oc + jj] : 0.f;
    }
    if (tid == 0) {
        sB1[0] = b1[0];
        sB1[1] = (oc >= 2) ? b1[1] : 0.f;
        sB1[2] = (oc >= 3) ? b1[2] : 0.f;
    }
    __syncthreads();

    int n = (blockIdx.x * 256 + tid) * 4;    // 4 rows per thread (NVOX % 4 == 0)
    if (n >= NVOX) return;
    const unsigned short* hp = hbuf + (size_t)(h * 64) * SROW + n;
    float x[4][3];
#pragma unroll
    for (int rr = 0; rr < 4; ++rr) { x[rr][0] = sB1[0]; x[rr][1] = sB1[1]; x[rr][2] = sB1[2]; }
#pragma unroll 8
    for (int cc = 0; cc < 64; ++cc) {
        uint2 raw = *(const uint2*)(hp + (size_t)cc * SROW);   // rows n..n+3, bf16
        float sc = sScale[cc], sh = sShift[cc];
        float w0 = sW1[cc * 3 + 0], w1 = sW1[cc * 3 + 1], w2 = sW1[cc * 3 + 2];
        float v0 = __builtin_bit_cast(float, raw.x << 16);
        float v1 = __builtin_bit_cast(float, raw.x & 0xffff0000u);
        float v2 = __builtin_bit_cast(float, raw.y << 16);
        float v3 = __builtin_bit_cast(float, raw.y & 0xffff0000u);
        v0 = fmaxf(v0 * sc + sh, 0.f); v1 = fmaxf(v1 * sc + sh, 0.f);
        v2 = fmaxf(v2 * sc + sh, 0.f); v3 = fmaxf(v3 * sc + sh, 0.f);
        x[0][0] += v0 * w0; x[0][1] += v0 * w1; x[0][2] += v0 * w2;
        x[1][0] += v1 * w0; x[1][1] += v1 * w1; x[1][2] += v1 * w2;
        x[2][0] += v2 * w0; x[2][1] += v2 * w1; x[2][2] += v2 * w2;
        x[3][0] += v3 * w0; x[3][1] += v3 * w1; x[3][2] += v3 * w2;
    }
#pragma unroll
    for (int rr = 0; rr < 4; ++rr) {
        float* op = out + obase + (size_t)(n + rr) * oc;
        op[0] = x[rr][0];                 // oc is block-uniform; x indices all static
        if (oc >= 2) op[1] = x[rr][1];
        if (oc >= 3) op[2] = x[rr][2];
    }
}

extern "C" void kernel_launch(void* const* d_in, const int* in_sizes, int n_in,
                              void* d_out, int out_size, void* d_ws, size_t ws_size,
                              hipStream_t stream) {
    const float* features = (const float*)d_in[0];
    const int* nbr        = (const int*)d_in[1];
    const float* w3       = (const float*)d_in[2];
    const float* gamma    = (const float*)d_in[3];
    const float* beta     = (const float*)d_in[4];
    const float* W1_0 = (const float*)d_in[5];  const float* b1_0 = (const float*)d_in[6];
    const float* W1_1 = (const float*)d_in[7];  const float* b1_1 = (const float*)d_in[8];
    const float* W1_2 = (const float*)d_in[9];  const float* b1_2 = (const float*)d_in[10];
    const float* W1_3 = (const float*)d_in[11]; const float* b1_3 = (const float*)d_in[12];
    const float* W1_4 = (const float*)d_in[13]; const float* b1_4 = (const float*)d_in[14];
    float* out = (float*)d_out;

    char* ws = (char*)d_ws;
    unsigned short* featB = (unsigned short*)ws;               // (150000+1)*64 bf16
    unsigned short* Bt2   = (unsigned short*)(ws + 19200128);  // 5*9*8*512 bf16
    float* stats          = (float*)(ws + 19568768);           // 640 f32
    unsigned short* hbuf  = (unsigned short*)(ws + 19571328);  // 320*150016 bf16
    // partials after hbuf: 1172*640 f32 = 3000320 B; total need = 118581888 B
    constexpr size_t PART_OFF = 19571328 + (size_t)NCOL * SROW * 2;  // 115581568
    float* partials = nullptr;
    if (ws_size >= PART_OFF + (size_t)MTILES * 2 * NCOL * 4)
        partials = (float*)(ws + PART_OFF);

    prep_feat<<<(NVOX * 8 + 8 + 255) / 256, 256, 0, stream>>>(features, featB);
    prep_w3<<<184320 / 256, 256, 0, stream>>>(w3, Bt2, stats);
    gemm_kernel<<<MTILES, 512, 0, stream>>>(featB, Bt2, nbr, hbuf, stats, partials);
    if (partials)
        stats_reduce<<<20, 256, 0, stream>>>(partials, stats);
    head_kernel<<<dim3(147, 5), 256, 0, stream>>>(hbuf, stats, gamma, beta,
        W1_0, W1_1, W1_2, W1_3, W1_4, b1_0, b1_1, b1_2, b1_3, b1_4, out);
}

// Round 7
// 236.759 us; speedup vs baseline: 1.0830x; 1.0592x over previous
//
#include <hip/hip_runtime.h>

#define NVOX 150000
#define BM 128
#define MTILES 1172         // ceil(150000/128)
#define NCOL 320
#define HROWS 150016        // 1172*128 rows in row-major hbuf

typedef __attribute__((ext_vector_type(8))) short bf16x8;
typedef __attribute__((ext_vector_type(4))) float f32x4;

__device__ __forceinline__ unsigned short f2bf(float f) {
    unsigned u = __builtin_bit_cast(unsigned, f);
    u += 0x7fffu + ((u >> 16) & 1u);
    return (unsigned short)(u >> 16);
}

__device__ __forceinline__ float bf2f(unsigned short u) {
    return __builtin_bit_cast(float, (unsigned)u << 16);
}

__device__ __forceinline__ void gld16(const void* g, void* l) {
    __builtin_amdgcn_global_load_lds(
        (const __attribute__((address_space(1))) unsigned int*)g,
        (__attribute__((address_space(3))) unsigned int*)l, 16, 0, 0);
}

// ---------------- prep: features f32 -> bf16 (+ zero row at NVOX), x8 vectorized ------
__global__ void prep_feat(const float* __restrict__ src, unsigned short* __restrict__ dst) {
    int i = blockIdx.x * 256 + threadIdx.x;   // each i handles 8 elements
    if (i < NVOX * 8) {
        const float* s = src + (size_t)i * 8;
        float4 a = *(const float4*)s;
        float4 b = *(const float4*)(s + 4);
        union { bf16x8 v; unsigned short u[8]; } r;
        r.u[0] = f2bf(a.x); r.u[1] = f2bf(a.y); r.u[2] = f2bf(a.z); r.u[3] = f2bf(a.w);
        r.u[4] = f2bf(b.x); r.u[5] = f2bf(b.y); r.u[6] = f2bf(b.z); r.u[7] = f2bf(b.w);
        *(bf16x8*)(dst + (size_t)i * 8) = r.v;
    } else if (i < NVOX * 8 + 8) {            // zero row for invalid/pad gathers
        bf16x8 z = {0, 0, 0, 0, 0, 0, 0, 0};
        *(bf16x8*)(dst + (size_t)i * 8) = z;
    }
}

// ---- prep: W3[h][kk][c][o] f32 -> Bt2 chunk-major bf16: [(h*9+kk)*8 + c16][o][c&7] ----
__global__ void prep_w3(const float* __restrict__ w3, unsigned short* __restrict__ bt,
                        float* __restrict__ stats) {
    int i = blockIdx.x * 256 + threadIdx.x;   // grid is exactly 184320 threads
    int h = i / 36864;
    int rem = i - h * 36864;
    int kk = rem >> 12;
    int c = (rem >> 6) & 63;
    int o = rem & 63;
    bt[(size_t)(((h * 9 + kk) * 8) + (c >> 3)) * 512 + o * 8 + (c & 7)] = f2bf(w3[i]);
    if (i < 2 * NCOL) stats[i] = 0.f;
}

// ---------------- gather-GEMM: R6 core + SWAPPED MFMA -> row-major hbuf ---------------
// mfma(bf, af): operand frag layouts are symmetric (both: lane&15 <-> 16-dim,
// lane>>4 <-> K-quarter), so swapping is legal; swapped C-mapping gives each lane
// 4 CONSECUTIVE OUTPUT COLS of one row (row=m16, cols=quad*4+reg) -> row-major
// epilogue with one ds_write_b64 per frag (conflict-free, 656B padded rows) and
// 4KB-contiguous hbuf[n][320] stores. Enables the streaming head_kernel.
__global__ __launch_bounds__(512, 2)
void gemm_kernel(const unsigned short* __restrict__ featB,
                 const unsigned short* __restrict__ Bt2,
                 const int* __restrict__ nbr,
                 unsigned short* __restrict__ hbuf,
                 float* __restrict__ stats,
                 float* __restrict__ partials) {
    __shared__ __align__(16) char smem[119296];
    constexpr int SB_OFF = 32768;    // B dbuf 2x40960
    constexpr int IDX_OFF = 114688;  // 9*128 int byte-offsets (4608 B)
    constexpr int SRED_OFF = 83968;  // stats staging 640*8 B; above row-major 128*656

    int mtile = blockIdx.x;
    int m0 = mtile * BM;

    int tid = threadIdx.x;
    int w = tid >> 6, lane = tid & 63;
    int quad = lane >> 4, m16 = lane & 15;

    // ---- stage neighbor byte-offset table: sIdx[kk][row] = srow*128 ----
    for (int lin = tid; lin < BM * 9; lin += 512) {
        int row = lin / 9, kkq = lin - row * 9;
        int v = -1;
        if (m0 + row < NVOX) v = nbr[(size_t)(m0 + row) * 9 + kkq];
        *(int*)(smem + IDX_OFF + (kkq * BM + row) * 4) = ((v < 0) ? NVOX : v) * 128;
    }
    __syncthreads();

    f32x4 acc[4][5];
#pragma unroll
    for (int mt = 0; mt < 4; ++mt)
#pragma unroll
        for (int nt = 0; nt < 5; ++nt)
            acc[mt][nt] = (f32x4){0.f, 0.f, 0.f, 0.f};

    const char* fb = (const char*)featB;
    const char* bt = (const char*)Bt2;
    char* sAb[2] = {smem, smem + 16384};
    char* sBb[2] = {smem + SB_OFF, smem + SB_OFF + 40960};

    int mrow = (w >> 2) * 64;    // wave's row half (0/64)
    int cbase = (w & 3) * 80;    // wave's 80-col quarter of the 320 cols

    // gather geometry: 8 lanes per row; lane = rloc*8 + j
    int rloc = lane >> 3, j = lane & 7;
    int jx = (j ^ rloc) * 16;    // source-chunk XOR swizzle ((row&7) == rloc)

    // B stage units for this wave: u = w*5+j -> (head, c16); 8 waves x 5 = 40 KB/kk
    int bsj[5], bdj[5];
#pragma unroll
    for (int jj = 0; jj < 5; ++jj) {
        int u = w * 5 + jj;
        int h = u >> 3, c16 = u & 7;
        bsj[jj] = (h * 72 + c16) * 1024 + lane * 16;  // + kk*8192 per tile
        bdj[jj] = (h * 8 + c16) * 1024;
    }
    // per-lane B-frag byte offsets within sB: col -> (head, o) chunk-major
    int sBoff[5];
#pragma unroll
    for (int nt = 0; nt < 5; ++nt) {
        int c = cbase + nt * 16 + m16;
        sBoff[nt] = (c >> 6) * 8192 + (c & 63) * 16;
    }
    // per-lane A-frag row bases (row-major) + XOR term per ds_read
    int aRow[4];
#pragma unroll
    for (int mt = 0; mt < 4; ++mt)
        aRow[mt] = (mrow + mt * 16 + m16) * 128;
    int axor = m16 & 7;          // == row & 7 for all frag rows

    auto stage = [&](int buf, int kk) {
        char* sA = sAb[buf];
        char* sB = sBb[buf];
        int off0 = *(const int*)(smem + IDX_OFF + (kk * BM + w * 16 + rloc) * 4);
        int off1 = *(const int*)(smem + IDX_OFF + (kk * BM + w * 16 + 8 + rloc) * 4);
        gld16(fb + off0 + jx, sA + w * 2048);
        gld16(fb + off1 + jx, sA + w * 2048 + 1024);
#pragma unroll
        for (int jj = 0; jj < 5; ++jj)
            gld16(bt + (size_t)(bsj[jj] + kk * 8192), sB + bdj[jj]);
    };

    // prologue: stage tile 0 (7 vm ops in flight)
    stage(0, 0);

#pragma unroll
    for (int kk = 0; kk < 9; ++kk) {
        const int p = kk & 1;
        if (kk < 8) {
            stage(p ^ 1, kk + 1);                      // 7 more vm ops (14 in flight)
            asm volatile("s_waitcnt vmcnt(7)" ::: "memory");  // tile kk done; kk+1 flies
        } else {
            asm volatile("s_waitcnt vmcnt(0)" ::: "memory");
        }
        asm volatile("s_barrier" ::: "memory");        // raw barrier: NO vmcnt drain
        __builtin_amdgcn_sched_barrier(0);             // rule 18: pin ds_read/MFMA below
        __builtin_amdgcn_s_setprio(1);
#pragma unroll
        for (int ks = 0; ks < 2; ++ks) {
            bf16x8 af[4], bf[5];
            int xq = ((ks * 4 + quad) ^ axor) * 16;    // swizzled chunk within row
#pragma unroll
            for (int mt = 0; mt < 4; ++mt)
                af[mt] = *(const bf16x8*)(sAb[p] + aRow[mt] + xq);
#pragma unroll
            for (int nt = 0; nt < 5; ++nt)
                bf[nt] = *(const bf16x8*)(sBb[p] + sBoff[nt] + (ks * 4 + quad) * 1024);
#pragma unroll
            for (int mt = 0; mt < 4; ++mt)
#pragma unroll
                for (int nt = 0; nt < 5; ++nt)
                    acc[mt][nt] = __builtin_amdgcn_mfma_f32_16x16x32_bf16(
                        bf[nt], af[mt], acc[mt][nt], 0, 0, 0);   // SWAPPED operands
        }
        __builtin_amdgcn_s_setprio(0);
        __builtin_amdgcn_sched_barrier(0);
        asm volatile("s_barrier" ::: "memory");        // sAb[p]/sBb[p] free to restage
    }

    // ---- epilogue 1: row-major LDS tile (656B/row pad) + contiguous hbuf stores ----
    // Swapped C-layout: lane holds rows mrow+mt*16+m16, cols cbase+nt*16+quad*4+{0..3}
#pragma unroll
    for (int mt = 0; mt < 4; ++mt) {
        int row = mrow + mt * 16 + m16;
#pragma unroll
        for (int nt = 0; nt < 5; ++nt) {
            int col0 = cbase + nt * 16 + quad * 4;
            f32x4 v = acc[mt][nt];
            unsigned lo = (unsigned)f2bf(v.x) | ((unsigned)f2bf(v.y) << 16);
            unsigned hi = (unsigned)f2bf(v.z) | ((unsigned)f2bf(v.w) << 16);
            uint2 pk; pk.x = lo; pk.y = hi;
            *(uint2*)(smem + row * 656 + col0 * 2) = pk;   // one b64, conflict-free
        }
    }
    __syncthreads();
#pragma unroll
    for (int it = 0; it < 20; ++it) {                  // 80KB tile: 4KB contiguous/iter
        int lin = it * 512 + tid;
        int row = lin / 80, k = lin - row * 80;
        uint2 v = *(const uint2*)(smem + row * 656 + k * 8);
        *(uint2*)(hbuf + (size_t)(m0 + row) * NCOL + k * 4) = v;
    }

    // ---- epilogue 2: BN statistics (pad/invalid rows are exact zeros) ----
    // col = cbase+nt*16+quad*4+jj; sum over mt (in-thread) and m16 (16-lane shfl tree)
#pragma unroll
    for (int nt = 0; nt < 5; ++nt) {
        float sj[4] = {0.f, 0.f, 0.f, 0.f}, ssj[4] = {0.f, 0.f, 0.f, 0.f};
#pragma unroll
        for (int mt = 0; mt < 4; ++mt) {
            f32x4 v = acc[mt][nt];
            sj[0] += v.x; ssj[0] += v.x * v.x;
            sj[1] += v.y; ssj[1] += v.y * v.y;
            sj[2] += v.z; ssj[2] += v.z * v.z;
            sj[3] += v.w; ssj[3] += v.w * v.w;
        }
#pragma unroll
        for (int jj = 0; jj < 4; ++jj) {
#pragma unroll
            for (int d = 1; d < 16; d <<= 1) {        // stays within the 16-lane group
                sj[jj] += __shfl_xor(sj[jj], d);
                ssj[jj] += __shfl_xor(ssj[jj], d);
            }
        }
        if (m16 == 0) {
#pragma unroll
            for (int jj = 0; jj < 4; ++jj) {
                float* p = (float*)(smem + SRED_OFF +
                                    (w * 80 + nt * 16 + quad * 4 + jj) * 8);
                p[0] = sj[jj]; p[1] = ssj[jj];
            }
        }
    }
    __syncthreads();
    if (tid < NCOL) {
        int c = tid;
        int qq = c / 80, lc = c - qq * 80;   // waves qq (rows 0-63) and qq+4 (64-127)
        const float* p0 = (const float*)(smem + SRED_OFF + (qq * 80 + lc) * 8);
        const float* p1 = (const float*)(smem + SRED_OFF + ((qq + 4) * 80 + lc) * 8);
        float vsum = p0[0] + p1[0];
        float vss  = p0[1] + p1[1];
        if (partials) {
            float* pp = partials + (size_t)mtile * (2 * NCOL);
            pp[c] = vsum;                // coalesced, no atomics
            pp[NCOL + c] = vss;
        } else {
            atomicAdd(&stats[c], vsum);
            atomicAdd(&stats[NCOL + c], vss);
        }
    }
}

// ---- stats_reduce: WIDE version (R6's 20-block one was ~44us latency-bound) ----
// grid (20, 8): 160 blocks; each covers 32 cols x ~19 mtiles/thread, LDS combine,
// then 5120 spread atomics (8 per address) into zeroed stats.
__global__ __launch_bounds__(256)
void stats_reduce(const float* __restrict__ partials, float* __restrict__ stats) {
    __shared__ float red[256];
    int tid = threadIdx.x;
    int cl = tid & 31, sc = tid >> 5;
    int jcol = blockIdx.x * 32 + cl;
    int ybase = blockIdx.y * 147;
    int mlo = ybase + sc * 19;
    int mhi = ybase + 147; if (mhi > MTILES) mhi = MTILES;
    int mend = mlo + 19; if (mend > mhi) mend = mhi;
    float s = 0.f;
    for (int m = mlo; m < mend; ++m)
        s += partials[(size_t)m * (2 * NCOL) + jcol];
    red[tid] = s;
    __syncthreads();
    if (tid < 32) {
        float a = red[tid];
#pragma unroll
        for (int k = 1; k < 8; ++k) a += red[k * 32 + tid];
        atomicAdd(&stats[blockIdx.x * 32 + tid], a);
    }
}

// ------- pass 2: STREAMING head. hbuf row-major [n][320]; thread = (row, head):
// 8 independent bf16x8 loads of a contiguous 128B slice, 64 FMA-triples, <=3 stores.
// 2930 blocks (~45 waves/CU), full line utilization, zero strided walks.
__global__ __launch_bounds__(256)
void head_kernel(const unsigned short* __restrict__ hbuf,
                 const float* __restrict__ stats,
                 const float* __restrict__ gamma, const float* __restrict__ beta,
                 const float* __restrict__ W1_0, const float* __restrict__ W1_1,
                 const float* __restrict__ W1_2, const float* __restrict__ W1_3,
                 const float* __restrict__ W1_4,
                 const float* __restrict__ b1_0, const float* __restrict__ b1_1,
                 const float* __restrict__ b1_2, const float* __restrict__ b1_3,
                 const float* __restrict__ b1_4,
                 float* __restrict__ out) {
    __shared__ float sScale[64], sShift[64], sW1[192], sB1[3];
    int h = blockIdx.y;
    const float* W1; const float* b1; int oc; size_t obase;
    if (h == 0)      { W1 = W1_0; b1 = b1_0; oc = 3; obase = 0; }
    else if (h == 1) { W1 = W1_1; b1 = b1_1; oc = 2; obase = 450000; }
    else if (h == 2) { W1 = W1_2; b1 = b1_2; oc = 1; obase = 750000; }
    else if (h == 3) { W1 = W1_3; b1 = b1_3; oc = 3; obase = 900000; }
    else             { W1 = W1_4; b1 = b1_4; oc = 2; obase = 1350000; }

    int tid = threadIdx.x;
    if (tid < 64) {
        int c = h * 64 + tid;
        float mean = stats[c] * (1.f / (float)NVOX);
        float var = stats[NCOL + c] * (1.f / (float)NVOX) - mean * mean;
        float inv = rsqrtf(var + 1e-5f);
        float sc = inv * gamma[c];
        sScale[tid] = sc;
        sShift[tid] = beta[c] - mean * sc;
    }
    for (int i = tid; i < 192; i += 256) {
        int cc = i / 3, jj = i - cc * 3;
        sW1[i] = (jj < oc) ? W1[cc * oc + jj] : 0.f;
    }
    if (tid == 0) {
        sB1[0] = b1[0];
        sB1[1] = (oc >= 2) ? b1[1] : 0.f;
        sB1[2] = (oc >= 3) ? b1[2] : 0.f;
    }
    __syncthreads();

    int n = blockIdx.x * 256 + tid;
    if (n >= NVOX) return;
    const unsigned short* hp = hbuf + (size_t)n * NCOL + h * 64;
    bf16x8 r[8];
#pragma unroll
    for (int jv = 0; jv < 8; ++jv)       // 8 independent 16B loads (contiguous 128B)
        r[jv] = *(const bf16x8*)(hp + jv * 8);
    float x0 = sB1[0], x1 = sB1[1], x2 = sB1[2];
#pragma unroll
    for (int jv = 0; jv < 8; ++jv) {
#pragma unroll
        for (int e = 0; e < 8; ++e) {
            int cc = jv * 8 + e;
            float v = bf2f((unsigned short)r[jv][e]);
            v = fmaxf(v * sScale[cc] + sShift[cc], 0.f);
            x0 += v * sW1[cc * 3 + 0];
            x1 += v * sW1[cc * 3 + 1];
            x2 += v * sW1[cc * 3 + 2];
        }
    }
    float* op = out + obase + (size_t)n * oc;
    op[0] = x0;
    if (oc >= 2) op[1] = x1;
    if (oc >= 3) op[2] = x2;
}

extern "C" void kernel_launch(void* const* d_in, const int* in_sizes, int n_in,
                              void* d_out, int out_size, void* d_ws, size_t ws_size,
                              hipStream_t stream) {
    const float* features = (const float*)d_in[0];
    const int* nbr        = (const int*)d_in[1];
    const float* w3       = (const float*)d_in[2];
    const float* gamma    = (const float*)d_in[3];
    const float* beta     = (const float*)d_in[4];
    const float* W1_0 = (const float*)d_in[5];  const float* b1_0 = (const float*)d_in[6];
    const float* W1_1 = (const float*)d_in[7];  const float* b1_1 = (const float*)d_in[8];
    const float* W1_2 = (const float*)d_in[9];  const float* b1_2 = (const float*)d_in[10];
    const float* W1_3 = (const float*)d_in[11]; const float* b1_3 = (const float*)d_in[12];
    const float* W1_4 = (const float*)d_in[13]; const float* b1_4 = (const float*)d_in[14];
    float* out = (float*)d_out;

    char* ws = (char*)d_ws;
    unsigned short* featB = (unsigned short*)ws;               // (150000+1)*64 bf16
    unsigned short* Bt2   = (unsigned short*)(ws + 19200128);  // 5*9*8*512 bf16
    float* stats          = (float*)(ws + 19568768);           // 640 f32
    unsigned short* hbuf  = (unsigned short*)(ws + 19571328);  // row-major [150016][320]
    constexpr size_t PART_OFF = 19571328 + (size_t)NCOL * HROWS * 2;  // 115581568
    float* partials = nullptr;
    if (ws_size >= PART_OFF + (size_t)MTILES * 2 * NCOL * 4)
        partials = (float*)(ws + PART_OFF);

    prep_feat<<<(NVOX * 8 + 8 + 255) / 256, 256, 0, stream>>>(features, featB);
    prep_w3<<<184320 / 256, 256, 0, stream>>>(w3, Bt2, stats);
    gemm_kernel<<<MTILES, 512, 0, stream>>>(featB, Bt2, nbr, hbuf, stats, partials);
    if (partials)
        stats_reduce<<<dim3(20, 8), 256, 0, stream>>>(partials, stats);
    head_kernel<<<dim3((NVOX + 255) / 256, 5), 256, 0, stream>>>(hbuf, stats, gamma, beta,
        W1_0, W1_1, W1_2, W1_3, W1_4, b1_0, b1_1, b1_2, b1_3, b1_4, out);
}

// Round 8
// 224.704 us; speedup vs baseline: 1.1411x; 1.0536x over previous
//
#include <hip/hip_runtime.h>

#define NVOX 150000
#define BM 128
#define MTILES 1172         // ceil(150000/128)
#define NCOL 320
#define HROWS 150016        // 1172*128 rows in row-major hbuf

typedef __attribute__((ext_vector_type(8))) short bf16x8;
typedef __attribute__((ext_vector_type(4))) float f32x4;

__device__ __forceinline__ unsigned short f2bf(float f) {
    unsigned u = __builtin_bit_cast(unsigned, f);
    u += 0x7fffu + ((u >> 16) & 1u);
    return (unsigned short)(u >> 16);
}

__device__ __forceinline__ float bf2f(unsigned short u) {
    return __builtin_bit_cast(float, (unsigned)u << 16);
}

__device__ __forceinline__ void gld16(const void* g, void* l) {
    __builtin_amdgcn_global_load_lds(
        (const __attribute__((address_space(1))) unsigned int*)g,
        (__attribute__((address_space(3))) unsigned int*)l, 16, 0, 0);
}

// ---------------- prep: features f32 -> bf16 (+ zero row at NVOX), x8 vectorized ------
__global__ void prep_feat(const float* __restrict__ src, unsigned short* __restrict__ dst) {
    int i = blockIdx.x * 256 + threadIdx.x;   // each i handles 8 elements
    if (i < NVOX * 8) {
        const float* s = src + (size_t)i * 8;
        float4 a = *(const float4*)s;
        float4 b = *(const float4*)(s + 4);
        union { bf16x8 v; unsigned short u[8]; } r;
        r.u[0] = f2bf(a.x); r.u[1] = f2bf(a.y); r.u[2] = f2bf(a.z); r.u[3] = f2bf(a.w);
        r.u[4] = f2bf(b.x); r.u[5] = f2bf(b.y); r.u[6] = f2bf(b.z); r.u[7] = f2bf(b.w);
        *(bf16x8*)(dst + (size_t)i * 8) = r.v;
    } else if (i < NVOX * 8 + 8) {            // zero row for invalid/pad gathers
        bf16x8 z = {0, 0, 0, 0, 0, 0, 0, 0};
        *(bf16x8*)(dst + (size_t)i * 8) = z;
    }
}

// ---- prep: W3[h][kk][c][o] f32 -> Bt2 chunk-major bf16: [(h*9+kk)*8 + c16][o][c&7] ----
__global__ void prep_w3(const float* __restrict__ w3, unsigned short* __restrict__ bt,
                        float* __restrict__ stats) {
    int i = blockIdx.x * 256 + threadIdx.x;   // grid is exactly 184320 threads
    int h = i / 36864;
    int rem = i - h * 36864;
    int kk = rem >> 12;
    int c = (rem >> 6) & 63;
    int o = rem & 63;
    bt[(size_t)(((h * 9 + kk) * 8) + (c >> 3)) * 512 + o * 8 + (c & 7)] = f2bf(w3[i]);
    if (i < 2 * NCOL) stats[i] = 0.f;
}

// ---------------- gather-GEMM: R7 core + sched fence isolating epilogue ---------------
// Swapped mfma(bf, af) -> row-major C layout (verified correct in R7): lane holds 4
// consecutive cols of one row. sched_barrier(0) after the K-loop keeps the epilogue's
// instructions out of the pipelined loop region (suspected source of R7's +15us).
__global__ __launch_bounds__(512, 2)
void gemm_kernel(const unsigned short* __restrict__ featB,
                 const unsigned short* __restrict__ Bt2,
                 const int* __restrict__ nbr,
                 unsigned short* __restrict__ hbuf,
                 float* __restrict__ stats,
                 float* __restrict__ partials) {
    __shared__ __align__(16) char smem[119296];
    constexpr int SB_OFF = 32768;    // B dbuf 2x40960
    constexpr int IDX_OFF = 114688;  // 9*128 int byte-offsets (4608 B)
    constexpr int SRED_OFF = 83968;  // stats staging 640*8 B; above row-major 128*656

    int mtile = blockIdx.x;
    int m0 = mtile * BM;

    int tid = threadIdx.x;
    int w = tid >> 6, lane = tid & 63;
    int quad = lane >> 4, m16 = lane & 15;

    // ---- stage neighbor byte-offset table: sIdx[kk][row] = srow*128 ----
    for (int lin = tid; lin < BM * 9; lin += 512) {
        int row = lin / 9, kkq = lin - row * 9;
        int v = -1;
        if (m0 + row < NVOX) v = nbr[(size_t)(m0 + row) * 9 + kkq];
        *(int*)(smem + IDX_OFF + (kkq * BM + row) * 4) = ((v < 0) ? NVOX : v) * 128;
    }
    __syncthreads();

    f32x4 acc[4][5];
#pragma unroll
    for (int mt = 0; mt < 4; ++mt)
#pragma unroll
        for (int nt = 0; nt < 5; ++nt)
            acc[mt][nt] = (f32x4){0.f, 0.f, 0.f, 0.f};

    const char* fb = (const char*)featB;
    const char* bt = (const char*)Bt2;
    char* sAb[2] = {smem, smem + 16384};
    char* sBb[2] = {smem + SB_OFF, smem + SB_OFF + 40960};

    int mrow = (w >> 2) * 64;    // wave's row half (0/64)
    int cbase = (w & 3) * 80;    // wave's 80-col quarter of the 320 cols

    // gather geometry: 8 lanes per row; lane = rloc*8 + j
    int rloc = lane >> 3, j = lane & 7;
    int jx = (j ^ rloc) * 16;    // source-chunk XOR swizzle ((row&7) == rloc)

    // B stage units for this wave: u = w*5+j -> (head, c16); 8 waves x 5 = 40 KB/kk
    int bsj[5], bdj[5];
#pragma unroll
    for (int jj = 0; jj < 5; ++jj) {
        int u = w * 5 + jj;
        int h = u >> 3, c16 = u & 7;
        bsj[jj] = (h * 72 + c16) * 1024 + lane * 16;  // + kk*8192 per tile
        bdj[jj] = (h * 8 + c16) * 1024;
    }
    // per-lane B-frag byte offsets within sB: col -> (head, o) chunk-major
    int sBoff[5];
#pragma unroll
    for (int nt = 0; nt < 5; ++nt) {
        int c = cbase + nt * 16 + m16;
        sBoff[nt] = (c >> 6) * 8192 + (c & 63) * 16;
    }
    // per-lane A-frag row bases (row-major) + XOR term per ds_read
    int aRow[4];
#pragma unroll
    for (int mt = 0; mt < 4; ++mt)
        aRow[mt] = (mrow + mt * 16 + m16) * 128;
    int axor = m16 & 7;          // == row & 7 for all frag rows

    auto stage = [&](int buf, int kk) {
        char* sA = sAb[buf];
        char* sB = sBb[buf];
        int off0 = *(const int*)(smem + IDX_OFF + (kk * BM + w * 16 + rloc) * 4);
        int off1 = *(const int*)(smem + IDX_OFF + (kk * BM + w * 16 + 8 + rloc) * 4);
        gld16(fb + off0 + jx, sA + w * 2048);
        gld16(fb + off1 + jx, sA + w * 2048 + 1024);
#pragma unroll
        for (int jj = 0; jj < 5; ++jj)
            gld16(bt + (size_t)(bsj[jj] + kk * 8192), sB + bdj[jj]);
    };

    // prologue: stage tile 0 (7 vm ops in flight)
    stage(0, 0);

#pragma unroll
    for (int kk = 0; kk < 9; ++kk) {
        const int p = kk & 1;
        if (kk < 8) {
            stage(p ^ 1, kk + 1);                      // 7 more vm ops (14 in flight)
            asm volatile("s_waitcnt vmcnt(7)" ::: "memory");  // tile kk done; kk+1 flies
        } else {
            asm volatile("s_waitcnt vmcnt(0)" ::: "memory");
        }
        asm volatile("s_barrier" ::: "memory");        // raw barrier: NO vmcnt drain
        __builtin_amdgcn_sched_barrier(0);             // rule 18: pin ds_read/MFMA below
        __builtin_amdgcn_s_setprio(1);
#pragma unroll
        for (int ks = 0; ks < 2; ++ks) {
            bf16x8 af[4], bf[5];
            int xq = ((ks * 4 + quad) ^ axor) * 16;    // swizzled chunk within row
#pragma unroll
            for (int mt = 0; mt < 4; ++mt)
                af[mt] = *(const bf16x8*)(sAb[p] + aRow[mt] + xq);
#pragma unroll
            for (int nt = 0; nt < 5; ++nt)
                bf[nt] = *(const bf16x8*)(sBb[p] + sBoff[nt] + (ks * 4 + quad) * 1024);
#pragma unroll
            for (int mt = 0; mt < 4; ++mt)
#pragma unroll
                for (int nt = 0; nt < 5; ++nt)
                    acc[mt][nt] = __builtin_amdgcn_mfma_f32_16x16x32_bf16(
                        bf[nt], af[mt], acc[mt][nt], 0, 0, 0);   // SWAPPED operands
        }
        __builtin_amdgcn_s_setprio(0);
        __builtin_amdgcn_sched_barrier(0);
        asm volatile("s_barrier" ::: "memory");        // sAb[p]/sBb[p] free to restage
    }
    __builtin_amdgcn_sched_barrier(0);   // fence: keep epilogue code out of the loop

    // ---- epilogue 1: row-major LDS tile (656B/row pad) + contiguous hbuf stores ----
    // Swapped C-layout: lane holds rows mrow+mt*16+m16, cols cbase+nt*16+quad*4+{0..3}
#pragma unroll
    for (int mt = 0; mt < 4; ++mt) {
        int row = mrow + mt * 16 + m16;
#pragma unroll
        for (int nt = 0; nt < 5; ++nt) {
            int col0 = cbase + nt * 16 + quad * 4;
            f32x4 v = acc[mt][nt];
            unsigned lo = (unsigned)f2bf(v.x) | ((unsigned)f2bf(v.y) << 16);
            unsigned hi = (unsigned)f2bf(v.z) | ((unsigned)f2bf(v.w) << 16);
            uint2 pk; pk.x = lo; pk.y = hi;
            *(uint2*)(smem + row * 656 + col0 * 2) = pk;   // one b64, ~2-way banks
        }
    }
    __syncthreads();
#pragma unroll
    for (int it = 0; it < 20; ++it) {                  // 80KB tile: 4KB contiguous/iter
        int lin = it * 512 + tid;
        int row = lin / 80, k = lin - row * 80;
        uint2 v = *(const uint2*)(smem + row * 656 + k * 8);
        *(uint2*)(hbuf + (size_t)(m0 + row) * NCOL + k * 4) = v;
    }

    // ---- epilogue 2: BN statistics (pad/invalid rows are exact zeros) ----
#pragma unroll
    for (int nt = 0; nt < 5; ++nt) {
        float sj[4] = {0.f, 0.f, 0.f, 0.f}, ssj[4] = {0.f, 0.f, 0.f, 0.f};
#pragma unroll
        for (int mt = 0; mt < 4; ++mt) {
            f32x4 v = acc[mt][nt];
            sj[0] += v.x; ssj[0] += v.x * v.x;
            sj[1] += v.y; ssj[1] += v.y * v.y;
            sj[2] += v.z; ssj[2] += v.z * v.z;
            sj[3] += v.w; ssj[3] += v.w * v.w;
        }
#pragma unroll
        for (int jj = 0; jj < 4; ++jj) {
#pragma unroll
            for (int d = 1; d < 16; d <<= 1) {        // stays within the 16-lane group
                sj[jj] += __shfl_xor(sj[jj], d);
                ssj[jj] += __shfl_xor(ssj[jj], d);
            }
        }
        if (m16 == 0) {
#pragma unroll
            for (int jj = 0; jj < 4; ++jj) {
                float* p = (float*)(smem + SRED_OFF +
                                    (w * 80 + nt * 16 + quad * 4 + jj) * 8);
                p[0] = sj[jj]; p[1] = ssj[jj];
            }
        }
    }
    __syncthreads();
    if (tid < NCOL) {
        int c = tid;
        int qq = c / 80, lc = c - qq * 80;   // waves qq (rows 0-63) and qq+4 (64-127)
        const float* p0 = (const float*)(smem + SRED_OFF + (qq * 80 + lc) * 8);
        const float* p1 = (const float*)(smem + SRED_OFF + ((qq + 4) * 80 + lc) * 8);
        float vsum = p0[0] + p1[0];
        float vss  = p0[1] + p1[1];
        if (partials) {
            float* pp = partials + (size_t)mtile * (2 * NCOL);
            pp[c] = vsum;                // coalesced, no atomics
            pp[NCOL + c] = vss;
        } else {
            atomicAdd(&stats[c], vsum);
            atomicAdd(&stats[NCOL + c], vss);
        }
    }
}

// ---- stats_reduce: wide (160 blocks), coalesced 128B/step reads, spread atomics ----
__global__ __launch_bounds__(256)
void stats_reduce(const float* __restrict__ partials, float* __restrict__ stats) {
    __shared__ float red[256];
    int tid = threadIdx.x;
    int cl = tid & 31, sc = tid >> 5;
    int jcol = blockIdx.x * 32 + cl;
    int ybase = blockIdx.y * 147;
    int mlo = ybase + sc * 19;
    int mhi = ybase + 147; if (mhi > MTILES) mhi = MTILES;
    int mend = mlo + 19; if (mend > mhi) mend = mhi;
    float s = 0.f;
    for (int m = mlo; m < mend; ++m)
        s += partials[(size_t)m * (2 * NCOL) + jcol];
    red[tid] = s;
    __syncthreads();
    if (tid < 32) {
        float a = red[tid];
#pragma unroll
        for (int k = 1; k < 8; ++k) a += red[k * 32 + tid];
        atomicAdd(&stats[blockIdx.x * 32 + tid], a);
    }
}

// ------- pass 2: BN + ReLU + 1x1 conv, 8-LANES-PER-ROW (16 full lines/instr) -------
// R7's streaming head kept lane-stride 640B -> 64 lines/instr (worst per-instr
// coalescing; head stuck ~110us like the strided one). Now lane l loads chunk l&7 of
// row l>>3: one instr = 8 rows x 128B contiguous = 16 fully-used lines (4x fewer
// requests). Per-lane register weights; 3-step shfl_xor sums the 8-lane group; lane
// j<oc writes component j (coalesced-ish 4B runs).
__global__ __launch_bounds__(256)
void head_kernel(const unsigned short* __restrict__ hbuf,
                 const float* __restrict__ stats,
                 const float* __restrict__ gamma, const float* __restrict__ beta,
                 const float* __restrict__ W1_0, const float* __restrict__ W1_1,
                 const float* __restrict__ W1_2, const float* __restrict__ W1_3,
                 const float* __restrict__ W1_4,
                 const float* __restrict__ b1_0, const float* __restrict__ b1_1,
                 const float* __restrict__ b1_2, const float* __restrict__ b1_3,
                 const float* __restrict__ b1_4,
                 float* __restrict__ out) {
    __shared__ float sScale[64], sShift[64], sW1[192], sB1[3];
    int h = blockIdx.y;
    const float* W1; const float* b1; int oc; size_t obase;
    if (h == 0)      { W1 = W1_0; b1 = b1_0; oc = 3; obase = 0; }
    else if (h == 1) { W1 = W1_1; b1 = b1_1; oc = 2; obase = 450000; }
    else if (h == 2) { W1 = W1_2; b1 = b1_2; oc = 1; obase = 750000; }
    else if (h == 3) { W1 = W1_3; b1 = b1_3; oc = 3; obase = 900000; }
    else             { W1 = W1_4; b1 = b1_4; oc = 2; obase = 1350000; }

    int tid = threadIdx.x;
    if (tid < 64) {
        int c = h * 64 + tid;
        float mean = stats[c] * (1.f / (float)NVOX);
        float var = stats[NCOL + c] * (1.f / (float)NVOX) - mean * mean;
        float inv = rsqrtf(var + 1e-5f);
        float sc = inv * gamma[c];
        sScale[tid] = sc;
        sShift[tid] = beta[c] - mean * sc;
    }
    for (int i = tid; i < 192; i += 256) {
        int cc = i / 3, jj = i - cc * 3;
        sW1[i] = (jj < oc) ? W1[cc * oc + jj] : 0.f;
    }
    if (tid == 0) {
        sB1[0] = b1[0];
        sB1[1] = (oc >= 2) ? b1[1] : 0.f;
        sB1[2] = (oc >= 3) ? b1[2] : 0.f;
    }
    __syncthreads();

    int lane = tid & 63, wv = tid >> 6;
    int j = lane & 7, r8 = lane >> 3;
    // per-lane channel params (channels j*8..j*8+7 of head h), pulled to registers once
    float wq0[8], wq1[8], wq2[8], scv[8], shv[8];
#pragma unroll
    for (int e = 0; e < 8; ++e) {
        int cc = j * 8 + e;
        scv[e] = sScale[cc]; shv[e] = sShift[cc];
        wq0[e] = sW1[cc * 3 + 0]; wq1[e] = sW1[cc * 3 + 1]; wq2[e] = sW1[cc * 3 + 2];
    }
    float b0 = sB1[0], b1v = sB1[1], b2 = sB1[2];

    int rowbase = blockIdx.x * 256 + wv * 8 + r8;      // + p*32 per pass
#pragma unroll
    for (int p = 0; p < 8; ++p) {
        int row = rowbase + p * 32;
        bf16x8 r = *(const bf16x8*)(hbuf + (size_t)row * NCOL + h * 64 + j * 8);
        float x0 = 0.f, x1 = 0.f, x2 = 0.f;
#pragma unroll
        for (int e = 0; e < 8; ++e) {
            float v = bf2f((unsigned short)r[e]);
            v = fmaxf(v * scv[e] + shv[e], 0.f);
            x0 += v * wq0[e]; x1 += v * wq1[e]; x2 += v * wq2[e];
        }
        x0 += __shfl_xor(x0, 1); x0 += __shfl_xor(x0, 2); x0 += __shfl_xor(x0, 4);
        x1 += __shfl_xor(x1, 1); x1 += __shfl_xor(x1, 2); x1 += __shfl_xor(x1, 4);
        x2 += __shfl_xor(x2, 1); x2 += __shfl_xor(x2, 2); x2 += __shfl_xor(x2, 4);
        if (row < NVOX && j < oc) {
            float xv = (j == 0) ? (x0 + b0) : (j == 1) ? (x1 + b1v) : (x2 + b2);
            out[obase + (size_t)row * oc + j] = xv;
        }
    }
}

extern "C" void kernel_launch(void* const* d_in, const int* in_sizes, int n_in,
                              void* d_out, int out_size, void* d_ws, size_t ws_size,
                              hipStream_t stream) {
    const float* features = (const float*)d_in[0];
    const int* nbr        = (const int*)d_in[1];
    const float* w3       = (const float*)d_in[2];
    const float* gamma    = (const float*)d_in[3];
    const float* beta     = (const float*)d_in[4];
    const float* W1_0 = (const float*)d_in[5];  const float* b1_0 = (const float*)d_in[6];
    const float* W1_1 = (const float*)d_in[7];  const float* b1_1 = (const float*)d_in[8];
    const float* W1_2 = (const float*)d_in[9];  const float* b1_2 = (const float*)d_in[10];
    const float* W1_3 = (const float*)d_in[11]; const float* b1_3 = (const float*)d_in[12];
    const float* W1_4 = (const float*)d_in[13]; const float* b1_4 = (const float*)d_in[14];
    float* out = (float*)d_out;

    char* ws = (char*)d_ws;
    unsigned short* featB = (unsigned short*)ws;               // (150000+1)*64 bf16
    unsigned short* Bt2   = (unsigned short*)(ws + 19200128);  // 5*9*8*512 bf16
    float* stats          = (float*)(ws + 19568768);           // 640 f32
    unsigned short* hbuf  = (unsigned short*)(ws + 19571328);  // row-major [150016][320]
    constexpr size_t PART_OFF = 19571328 + (size_t)NCOL * HROWS * 2;  // 115581568
    float* partials = nullptr;
    if (ws_size >= PART_OFF + (size_t)MTILES * 2 * NCOL * 4)
        partials = (float*)(ws + PART_OFF);

    prep_feat<<<(NVOX * 8 + 8 + 255) / 256, 256, 0, stream>>>(features, featB);
    prep_w3<<<184320 / 256, 256, 0, stream>>>(w3, Bt2, stats);
    gemm_kernel<<<MTILES, 512, 0, stream>>>(featB, Bt2, nbr, hbuf, stats, partials);
    if (partials)
        stats_reduce<<<dim3(20, 8), 256, 0, stream>>>(partials, stats);
    head_kernel<<<dim3((NVOX + 255) / 256, 5), 256, 0, stream>>>(hbuf, stats, gamma, beta,
        W1_0, W1_1, W1_2, W1_3, W1_4, b1_0, b1_1, b1_2, b1_3, b1_4, out);
}

// Round 9
// 208.652 us; speedup vs baseline: 1.2289x; 1.0769x over previous
//
#include <hip/hip_runtime.h>

#define NVOX 150000
#define BM 128
#define MTILES 1172         // ceil(150000/128)
#define SROW 150016         // 1172*128, column stride of h buffer
#define NCOL 320

typedef __attribute__((ext_vector_type(8))) short bf16x8;
typedef __attribute__((ext_vector_type(4))) float f32x4;

__device__ __forceinline__ unsigned short f2bf(float f) {
    unsigned u = __builtin_bit_cast(unsigned, f);
    u += 0x7fffu + ((u >> 16) & 1u);
    return (unsigned short)(u >> 16);
}

__device__ __forceinline__ void gld16(const void* g, void* l) {
    __builtin_amdgcn_global_load_lds(
        (const __attribute__((address_space(1))) unsigned int*)g,
        (__attribute__((address_space(3))) unsigned int*)l, 16, 0, 0);
}

// ------------- merged prep: features->bf16 + W3 repack (one launch fewer) -------------
__global__ void prep_all(const float* __restrict__ src, unsigned short* __restrict__ dst,
                         const float* __restrict__ w3, unsigned short* __restrict__ bt,
                         float* __restrict__ stats) {
    int bid = blockIdx.x, tid = threadIdx.x;
    if (bid < 4688) {                         // features f32 -> bf16, x8 vectorized
        int i = bid * 256 + tid;
        if (i < NVOX * 8) {
            const float* s = src + (size_t)i * 8;
            float4 a = *(const float4*)s;
            float4 b = *(const float4*)(s + 4);
            union { bf16x8 v; unsigned short u[8]; } r;
            r.u[0] = f2bf(a.x); r.u[1] = f2bf(a.y); r.u[2] = f2bf(a.z); r.u[3] = f2bf(a.w);
            r.u[4] = f2bf(b.x); r.u[5] = f2bf(b.y); r.u[6] = f2bf(b.z); r.u[7] = f2bf(b.w);
            *(bf16x8*)(dst + (size_t)i * 8) = r.v;
        } else if (i < NVOX * 8 + 8) {        // zero row for invalid/pad gathers
            bf16x8 z = {0, 0, 0, 0, 0, 0, 0, 0};
            *(bf16x8*)(dst + (size_t)i * 8) = z;
        }
    } else {                                  // W3 -> chunk-major bf16 (+ stats zero)
        int i = (bid - 4688) * 256 + tid;     // exactly 184320 threads
        int h = i / 36864;
        int rem = i - h * 36864;
        int kk = rem >> 12;
        int c = (rem >> 6) & 63;
        int o = rem & 63;
        bt[(size_t)(((h * 9 + kk) * 8) + (c >> 3)) * 512 + o * 8 + (c & 7)] = f2bf(w3[i]);
        if (i < 2 * NCOL) stats[i] = 0.f;
    }
}

// ---------------- gather-GEMM: R6 core + A STAGED TWO TILES AHEAD ---------------------
// R6 (unswapped, col-major epilogue) measured 86us best. Remaining stall theory: the
// random-L3 A gather (~600-800cy) had only ONE compute phase (~390cy) of cover. Now:
// A tri-buffer (3x16KB), issue order per iter = B(kk+1) THEN A(kk+2), so in-order
// vmcnt retirement gives every A two full compute phases. Wait ladder (derived op-by-
// op, prologue A0,A1,B0): W = [7,9,9,9,9,9,9,7,0]. B keeps 1 phase (L2-hot, enough).
// LDS: sA 3x16K @0, sB 2x40K @49152, idx @131072 -> 135680 B, 1 block/CU (8 waves).
__global__ __launch_bounds__(512, 2)
void gemm_kernel(const unsigned short* __restrict__ featB,
                 const unsigned short* __restrict__ Bt2,
                 const int* __restrict__ nbr,
                 unsigned short* __restrict__ hbuf,
                 float* __restrict__ stats,
                 float* __restrict__ partials) {
    __shared__ __align__(16) char smem[135680];
    constexpr int SB_OFF = 49152;    // B dbuf 2x40960
    constexpr int IDX_OFF = 131072;  // 9*128 int byte-offsets (4608 B)
    constexpr int SRED_OFF = 88064;  // stats staging 640*8 B; above transpose's 87040

    int mtile = blockIdx.x;
    int m0 = mtile * BM;

    int tid = threadIdx.x;
    int w = tid >> 6, lane = tid & 63;
    int quad = lane >> 4, m16 = lane & 15;

    // ---- stage neighbor byte-offset table: sIdx[kk][row] = srow*128 ----
    for (int lin = tid; lin < BM * 9; lin += 512) {
        int row = lin / 9, kkq = lin - row * 9;
        int v = -1;
        if (m0 + row < NVOX) v = nbr[(size_t)(m0 + row) * 9 + kkq];
        *(int*)(smem + IDX_OFF + (kkq * BM + row) * 4) = ((v < 0) ? NVOX : v) * 128;
    }
    __syncthreads();

    f32x4 acc[4][5];
#pragma unroll
    for (int mt = 0; mt < 4; ++mt)
#pragma unroll
        for (int nt = 0; nt < 5; ++nt)
            acc[mt][nt] = (f32x4){0.f, 0.f, 0.f, 0.f};

    const char* fb = (const char*)featB;
    const char* bt = (const char*)Bt2;

    int mrow = (w >> 2) * 64;    // wave's row half (0/64)
    int cbase = (w & 3) * 80;    // wave's 80-col quarter of the 320 cols

    // gather geometry: 8 lanes per row; lane = rloc*8 + j
    int rloc = lane >> 3, j = lane & 7;
    int jx = (j ^ rloc) * 16;    // source-chunk XOR swizzle ((row&7) == rloc)

    // B stage units for this wave: u = w*5+j -> (head, c16); 8 waves x 5 = 40 KB/kk
    int bsj[5], bdj[5];
#pragma unroll
    for (int jj = 0; jj < 5; ++jj) {
        int u = w * 5 + jj;
        int h = u >> 3, c16 = u & 7;
        bsj[jj] = (h * 72 + c16) * 1024 + lane * 16;  // + kk*8192 per tile
        bdj[jj] = (h * 8 + c16) * 1024;
    }
    // per-lane B-frag byte offsets within sB: col -> (head, o) chunk-major
    int sBoff[5];
#pragma unroll
    for (int nt = 0; nt < 5; ++nt) {
        int c = cbase + nt * 16 + m16;
        sBoff[nt] = (c >> 6) * 8192 + (c & 63) * 16;
    }
    // per-lane A-frag row bases (row-major) + XOR term per ds_read
    int aRow[4];
#pragma unroll
    for (int mt = 0; mt < 4; ++mt)
        aRow[mt] = (mrow + mt * 16 + m16) * 128;
    int axor = m16 & 7;          // == row & 7 for all frag rows

    auto stageA = [&](int buf, int kk) {
        char* sA = smem + buf * 16384;
        int off0 = *(const int*)(smem + IDX_OFF + (kk * BM + w * 16 + rloc) * 4);
        int off1 = *(const int*)(smem + IDX_OFF + (kk * BM + w * 16 + 8 + rloc) * 4);
        gld16(fb + off0 + jx, sA + w * 2048);          // 2 ops: 16 full rows
        gld16(fb + off1 + jx, sA + w * 2048 + 1024);
    };
    auto stageB = [&](int buf, int kk) {
        char* sB = smem + SB_OFF + buf * 40960;
#pragma unroll
        for (int jj = 0; jj < 5; ++jj)                 // 5 ops, L2-hot sequential
            gld16(bt + (size_t)(bsj[jj] + kk * 8192), sB + bdj[jj]);
    };
    auto computeStep = [&](int pA, int pB) {
        const char* sA = smem + pA * 16384;
        const char* sB = smem + SB_OFF + pB * 40960;
#pragma unroll
        for (int ks = 0; ks < 2; ++ks) {
            bf16x8 af[4], bf[5];
            int xq = ((ks * 4 + quad) ^ axor) * 16;    // swizzled chunk within row
#pragma unroll
            for (int mt = 0; mt < 4; ++mt)
                af[mt] = *(const bf16x8*)(sA + aRow[mt] + xq);
#pragma unroll
            for (int nt = 0; nt < 5; ++nt)
                bf[nt] = *(const bf16x8*)(sB + sBoff[nt] + (ks * 4 + quad) * 1024);
#pragma unroll
            for (int mt = 0; mt < 4; ++mt)
#pragma unroll
                for (int nt = 0; nt < 5; ++nt)
                    acc[mt][nt] = __builtin_amdgcn_mfma_f32_16x16x32_bf16(
                        af[mt], bf[nt], acc[mt][nt], 0, 0, 0);
        }
    };

    // prologue: A(0), A(1), B(0) -> 9 ops in flight
    stageA(0, 0);
    stageA(1, 1);
    stageB(0, 0);

#define STR2(x) #x
#define VMCNT(N) asm volatile("s_waitcnt vmcnt(" STR2(N) ")" ::: "memory")
#define GEMM_STEP(KK, WN)                                                   \
    do {                                                                    \
        if ((KK) < 8) stageB((KK + 1) & 1, (KK) + 1);                       \
        if ((KK) < 7) stageA(((KK) + 2) % 3, (KK) + 2);                     \
        VMCNT(WN);                                                          \
        asm volatile("s_barrier" ::: "memory");                             \
        __builtin_amdgcn_sched_barrier(0);                                  \
        __builtin_amdgcn_s_setprio(1);                                      \
        computeStep((KK) % 3, (KK) & 1);                                    \
        __builtin_amdgcn_s_setprio(0);                                      \
        __builtin_amdgcn_sched_barrier(0);                                  \
        asm volatile("s_barrier" ::: "memory");                             \
    } while (0)

    GEMM_STEP(0, 7);
    GEMM_STEP(1, 9);
    GEMM_STEP(2, 9);
    GEMM_STEP(3, 9);
    GEMM_STEP(4, 9);
    GEMM_STEP(5, 9);
    GEMM_STEP(6, 9);
    GEMM_STEP(7, 7);
    GEMM_STEP(8, 0);
#undef GEMM_STEP
#undef VMCNT
#undef STR2
    __builtin_amdgcn_sched_barrier(0);   // keep epilogue out of the loop region

    // ---- epilogue 1: transpose via LDS (aliases dead sA/sB), coalesced column stores
#pragma unroll
    for (int mt = 0; mt < 4; ++mt) {
#pragma unroll
        for (int nt = 0; nt < 5; ++nt) {
            int col = cbase + nt * 16 + m16;
            int row = mrow + mt * 16 + quad * 4;
            f32x4 v = acc[mt][nt];
            unsigned lo = (unsigned)f2bf(v.x) | ((unsigned)f2bf(v.y) << 16);
            unsigned hi = (unsigned)f2bf(v.z) | ((unsigned)f2bf(v.w) << 16);
            uint2 pk; pk.x = lo; pk.y = hi;
            *(uint2*)(smem + col * 272 + row * 2) = pk;   // col stride 136 ushorts
        }
    }
    __syncthreads();
#pragma unroll
    for (int it = 0; it < 20; ++it) {                  // 320 cols = 20 x (16 cols x 32 ln)
        int col = it * 16 + (tid >> 5);
        int l32 = tid & 31;
        uint2 v = *(const uint2*)(smem + col * 272 + l32 * 8);
        *(uint2*)(hbuf + (size_t)col * SROW + m0 + l32 * 4) = v;  // 256B runs
    }

    // ---- epilogue 2: BN statistics (pad/invalid rows are exact zeros) ----
    float s[5], ss[5];
#pragma unroll
    for (int nt = 0; nt < 5; ++nt) {
        float a = 0.f, b = 0.f;
#pragma unroll
        for (int mt = 0; mt < 4; ++mt) {
            f32x4 v = acc[mt][nt];
            a += v.x + v.y + v.z + v.w;
            b += v.x * v.x + v.y * v.y + v.z * v.z + v.w * v.w;
        }
        s[nt] = a; ss[nt] = b;
        s[nt] += __shfl_xor(s[nt], 16); s[nt] += __shfl_xor(s[nt], 32);
        ss[nt] += __shfl_xor(ss[nt], 16); ss[nt] += __shfl_xor(ss[nt], 32);
    }
    if (quad == 0) {   // SRED region (88064+) disjoint from transpose (<87040) and idx
#pragma unroll
        for (int nt = 0; nt < 5; ++nt) {
            float* p = (float*)(smem + SRED_OFF + (w * 80 + nt * 16 + m16) * 8);
            p[0] = s[nt]; p[1] = ss[nt];
        }
    }
    __syncthreads();
    if (tid < NCOL) {
        int c = tid;
        int qq = c / 80, lc = c - qq * 80;   // waves qq (rows 0-63) and qq+4 (64-127)
        const float* p0 = (const float*)(smem + SRED_OFF + (qq * 80 + lc) * 8);
        const float* p1 = (const float*)(smem + SRED_OFF + ((qq + 4) * 80 + lc) * 8);
        float vsum = p0[0] + p1[0];
        float vss  = p0[1] + p1[1];
        if (partials) {
            float* pp = partials + (size_t)mtile * (2 * NCOL);
            pp[c] = vsum;                // coalesced, no atomics
            pp[NCOL + c] = vss;
        } else {
            atomicAdd(&stats[c], vsum);
            atomicAdd(&stats[NCOL + c], vss);
        }
    }
}

// ---- stats_reduce: wide (160 blocks), coalesced 128B/step reads, spread atomics ----
__global__ __launch_bounds__(256)
void stats_reduce(const float* __restrict__ partials, float* __restrict__ stats) {
    __shared__ float red[256];
    int tid = threadIdx.x;
    int cl = tid & 31, sc = tid >> 5;
    int jcol = blockIdx.x * 32 + cl;
    int ybase = blockIdx.y * 147;
    int mlo = ybase + sc * 19;
    int mhi = ybase + 147; if (mhi > MTILES) mhi = MTILES;
    int mend = mlo + 19; if (mend > mhi) mend = mhi;
    float s = 0.f;
    for (int m = mlo; m < mend; ++m)
        s += partials[(size_t)m * (2 * NCOL) + jcol];
    red[tid] = s;
    __syncthreads();
    if (tid < 32) {
        float a = red[tid];
#pragma unroll
        for (int k = 1; k < 8; ++k) a += red[k * 32 + tid];
        atomicAdd(&stats[blockIdx.x * 32 + tid], a);
    }
}

// ------- pass 2: BN + ReLU + 1x1 conv (R6's measured head: 4 rows/thread, coalesced
// 512B/wave-instr reads of column-major hbuf, per-head grid)
__global__ __launch_bounds__(256)
void head_kernel(const unsigned short* __restrict__ hbuf,
                 const float* __restrict__ stats,
                 const float* __restrict__ gamma, const float* __restrict__ beta,
                 const float* __restrict__ W1_0, const float* __restrict__ W1_1,
                 const float* __restrict__ W1_2, const float* __restrict__ W1_3,
                 const float* __restrict__ W1_4,
                 const float* __restrict__ b1_0, const float* __restrict__ b1_1,
                 const float* __restrict__ b1_2, const float* __restrict__ b1_3,
                 const float* __restrict__ b1_4,
                 float* __restrict__ out) {
    __shared__ float sScale[64], sShift[64], sW1[192], sB1[3];
    int h = blockIdx.y;
    const float* W1; const float* b1; int oc; size_t obase;
    if (h == 0)      { W1 = W1_0; b1 = b1_0; oc = 3; obase = 0; }
    else if (h == 1) { W1 = W1_1; b1 = b1_1; oc = 2; obase = 450000; }
    else if (h == 2) { W1 = W1_2; b1 = b1_2; oc = 1; obase = 750000; }
    else if (h == 3) { W1 = W1_3; b1 = b1_3; oc = 3; obase = 900000; }
    else             { W1 = W1_4; b1 = b1_4; oc = 2; obase = 1350000; }

    int tid = threadIdx.x;
    if (tid < 64) {
        int c = h * 64 + tid;
        float mean = stats[c] * (1.f / (float)NVOX);
        float var = stats[NCOL + c] * (1.f / (float)NVOX) - mean * mean;
        float inv = rsqrtf(var + 1e-5f);
        float sc = inv * gamma[c];
        sScale[tid] = sc;
        sShift[tid] = beta[c] - mean * sc;
    }
    for (int i = tid; i < 192; i += 256) {
        int cc = i / 3, jj = i - cc * 3;
        sW1[i] = (jj < oc) ? W1[cc * oc + jj] : 0.f;
    }
    if (tid == 0) {
        sB1[0] = b1[0];
        sB1[1] = (oc >= 2) ? b1[1] : 0.f;
        sB1[2] = (oc >= 3) ? b1[2] : 0.f;
    }
    __syncthreads();

    int n = (blockIdx.x * 256 + tid) * 4;    // 4 rows per thread (NVOX % 4 == 0)
    if (n >= NVOX) return;
    const unsigned short* hp = hbuf + (size_t)(h * 64) * SROW + n;
    float x[4][3];
#pragma unroll
    for (int rr = 0; rr < 4; ++rr) { x[rr][0] = sB1[0]; x[rr][1] = sB1[1]; x[rr][2] = sB1[2]; }
#pragma unroll 8
    for (int cc = 0; cc < 64; ++cc) {
        uint2 raw = *(const uint2*)(hp + (size_t)cc * SROW);   // rows n..n+3, bf16
        float sc = sScale[cc], sh = sShift[cc];
        float w0 = sW1[cc * 3 + 0], w1 = sW1[cc * 3 + 1], w2 = sW1[cc * 3 + 2];
        float v0 = __builtin_bit_cast(float, raw.x << 16);
        float v1 = __builtin_bit_cast(float, raw.x & 0xffff0000u);
        float v2 = __builtin_bit_cast(float, raw.y << 16);
        float v3 = __builtin_bit_cast(float, raw.y & 0xffff0000u);
        v0 = fmaxf(v0 * sc + sh, 0.f); v1 = fmaxf(v1 * sc + sh, 0.f);
        v2 = fmaxf(v2 * sc + sh, 0.f); v3 = fmaxf(v3 * sc + sh, 0.f);
        x[0][0] += v0 * w0; x[0][1] += v0 * w1; x[0][2] += v0 * w2;
        x[1][0] += v1 * w0; x[1][1] += v1 * w1; x[1][2] += v1 * w2;
        x[2][0] += v2 * w0; x[2][1] += v2 * w1; x[2][2] += v2 * w2;
        x[3][0] += v3 * w0; x[3][1] += v3 * w1; x[3][2] += v3 * w2;
    }
#pragma unroll
    for (int rr = 0; rr < 4; ++rr) {
        float* op = out + obase + (size_t)(n + rr) * oc;
        op[0] = x[rr][0];                 // oc is block-uniform; x indices all static
        if (oc >= 2) op[1] = x[rr][1];
        if (oc >= 3) op[2] = x[rr][2];
    }
}

extern "C" void kernel_launch(void* const* d_in, const int* in_sizes, int n_in,
                              void* d_out, int out_size, void* d_ws, size_t ws_size,
                              hipStream_t stream) {
    const float* features = (const float*)d_in[0];
    const int* nbr        = (const int*)d_in[1];
    const float* w3       = (const float*)d_in[2];
    const float* gamma    = (const float*)d_in[3];
    const float* beta     = (const float*)d_in[4];
    const float* W1_0 = (const float*)d_in[5];  const float* b1_0 = (const float*)d_in[6];
    const float* W1_1 = (const float*)d_in[7];  const float* b1_1 = (const float*)d_in[8];
    const float* W1_2 = (const float*)d_in[9];  const float* b1_2 = (const float*)d_in[10];
    const float* W1_3 = (const float*)d_in[11]; const float* b1_3 = (const float*)d_in[12];
    const float* W1_4 = (const float*)d_in[13]; const float* b1_4 = (const float*)d_in[14];
    float* out = (float*)d_out;

    char* ws = (char*)d_ws;
    unsigned short* featB = (unsigned short*)ws;               // (150000+1)*64 bf16
    unsigned short* Bt2   = (unsigned short*)(ws + 19200128);  // 5*9*8*512 bf16
    float* stats          = (float*)(ws + 19568768);           // 640 f32
    unsigned short* hbuf  = (unsigned short*)(ws + 19571328);  // col-major [320][150016]
    constexpr size_t PART_OFF = 19571328 + (size_t)NCOL * SROW * 2;  // 115581568
    float* partials = nullptr;
    if (ws_size >= PART_OFF + (size_t)MTILES * 2 * NCOL * 4)
        partials = (float*)(ws + PART_OFF);

    prep_all<<<4688 + 720, 256, 0, stream>>>(features, featB, w3, Bt2, stats);
    gemm_kernel<<<MTILES, 512, 0, stream>>>(featB, Bt2, nbr, hbuf, stats, partials);
    if (partials)
        stats_reduce<<<dim3(20, 8), 256, 0, stream>>>(partials, stats);
    head_kernel<<<dim3(147, 5), 256, 0, stream>>>(hbuf, stats, gamma, beta,
        W1_0, W1_1, W1_2, W1_3, W1_4, b1_0, b1_1, b1_2, b1_3, b1_4, out);
}